// Round 6
// baseline (118.804 us; speedup 1.0000x reference)
//
#include <hip/hip_runtime.h>

// EvalEig round 6: split the monolithic solve into 5 barrier-free dispatches
// (zero+gtable / segment-matrices / serial-combine / replay / finalize) with
// all cross-phase data in ws. Rounds 3/5 nulls (2x waves, -20% VALU, rcp
// removal) left the ~31us solve unexplained and invisible (top-5 = harness
// fills only). This exposes per-phase dur/VALUBusy/VGPR/FETCH and removes
// in-block barrier serialization. k_replay's 48 MB store stream becomes a
// clean HBM-bound kernel (~8us floor).

namespace {
constexpr int kNE    = 4096;
constexpr int kNCH   = kNE * 3;        // 12288 chains
constexpr int kMatch = 100;
constexpr float kC   = 3.0f / 40.0f * 0.01f;
constexpr float kK1  = 13.0f / 15.0f * 0.01f;
constexpr float kK2  = 7.0f / 60.0f * 0.01f;
constexpr int kSeg   = 32;             // 31 full 28-step segments + 26-step tail

// ws float offsets
constexpr size_t W_LF_IN = 0;                                // [12288]
constexpr size_t W_IG_IN = 12288;                            // [12288]
constexpr size_t W_GT    = 24576;                            // [899*3]
constexpr size_t W_MAT   = 32768;                            // [16][31][12288]
constexpr size_t W_ST    = W_MAT + (size_t)16 * 31 * 12288;  // [32][4][12288]
constexpr size_t W_A4    = W_ST  + (size_t)4 * 32 * 12288;   // [32][12288]
constexpr size_t W_A2    = W_A4  + (size_t)32 * 12288;       // [32][12288]
constexpr size_t W_HD    = W_A2  + (size_t)32 * 12288;       // [5][12288]
}

__device__ __forceinline__ float rcp_f(float x) { return __builtin_amdgcn_rcpf(x); }
__device__ __forceinline__ float rcp_nr(float x) {
    float r = __builtin_amdgcn_rcpf(x);
    return fmaf(fmaf(-x, r, 1.0f), r, r);
}

// shared step macros: GQ = pointer into g-table (stride 3 floats), negE in scope
#define COEF(GQ,FA,FB,FC,FD) \
    { float f4 = *GQ + negE; GQ += 3; \
      float x  = kC * f4; \
      float iv = fmaf(x, x, x) + 1.0f; \
      ca  = fmaf(kC  * FA, iv, -1.0f); \
      cb  = fmaf(kK1 * FB, iv,  2.0f); \
      cc_ = fmaf(kK2 * FC, iv, -2.0f); \
      cd  = fmaf(kK1 * FD, iv,  2.0f); \
      FA = f4; }

// ---------------------------------------------------------------- k_zero
__global__ __launch_bounds__(256) void k_zero(const float* __restrict__ energy,
                                              float* __restrict__ out,
                                              float* __restrict__ ws)
{
    const int t = (int)blockIdx.x * 256 + (int)threadIdx.x;

    // build global g-table: g(j,l) = l(l+1)/r^2 - 1/r, r = 100 - 0.1j
    if (t < 899) {
        float ri = rcp_nr(fmaf((float)t, -0.1f, 100.0f));
        ws[W_GT + t * 3 + 0] = -ri;
        ws[W_GT + t * 3 + 1] = ri * fmaf(2.0f, ri, -1.0f);
        ws[W_GT + t * 3 + 2] = ri * fmaf(6.0f, ri, -1.0f);
    }

    // u_zero outward solve: 94 steps, 1 thread/chain
    const int l  = t % 3;
    const int ei = t / 3;
    const float e = energy[ei], negE = -e;
    const float ll1 = (float)(l * (l + 1));
    const float rdiv = (l == 0) ? 0.5f : ((l == 1) ? 0.25f : (1.0f/6.0f));
    float* uzero = out + kNCH;
    float p0,p1,p2,p3,p4;
    {
        float pw[5];
        #pragma unroll
        for (int k = 0; k < 5; ++k) {
            float r = 0.1f * (float)(k + 1);
            float rl1 = (l == 0) ? r : ((l == 1) ? r*r : r*r*r);
            pw[k] = rl1 - (rl1 * r) * rdiv;
            uzero[(size_t)k * kNCH + t] = pw[k];
        }
        uzero[(size_t)5 * kNCH + t] = pw[4];
        p0=pw[0]; p1=pw[1]; p2=pw[2]; p3=pw[3]; p4=pw[4];
    }
    float acc4, acc2;
    {
        float q0=p0*p0, q1=p1*p1, q2=p2*p2, q3=p3*p3, q4=p4*p4;
        acc4 = 7.0f*q0*q0 + 32.0f*q1*q1 + 32.0f*q3*q3 + 14.0f*q4*q4 + 32.0f*q4*q4;
        acc2 = q2;
    }
    float f0, f1, f2, f3;
    {
        float i1 = rcp_f(0.2f), i2 = rcp_f(0.3f), i3 = rcp_f(0.4f), i4 = rcp_f(0.5f);
        f0 = fmaf(i1, fmaf(ll1, i1, -1.0f), negE);
        f1 = fmaf(i2, fmaf(ll1, i2, -1.0f), negE);
        f2 = fmaf(i3, fmaf(ll1, i3, -1.0f), negE);
        f3 = fmaf(i4, fmaf(ll1, i4, -1.0f), negE);
    }
    float* ptr = uzero + (size_t)6 * kNCH + t;
    #pragma unroll 4
    for (int j = 5; j <= 98; ++j) {
        float ri = rcp_f(fmaf((float)j, 0.1f, 0.1f));
        float f4 = fmaf(ri, fmaf(ll1, ri, -1.0f), negE);
        float iv = rcp_f(fmaf(-kC, f4, 1.0f));
        float a  = fmaf(kC  * f0, iv, -1.0f);
        float b  = fmaf(kK1 * f1, iv,  2.0f);
        float cc = fmaf(kK2 * f2, iv, -2.0f);
        float d  = fmaf(kK1 * f3, iv,  2.0f);
        float nw = fmaf(d, p4, fmaf(cc, p3, fmaf(b, p2, a * p1)));
        *ptr = nw; ptr += kNCH;
        float v2 = nw*nw, v4 = v2*v2;
        if (j <= 94) {
            int m = (j + 1) & 3;
            if (m == 2)      acc2 += v2;
            else if (m == 0) acc4 += 14.0f * v4;
            else             acc4 += 32.0f * v4;
        } else if (j == 95) {
            acc4 += 7.0f * v4;
        }
        f0 = f1; f1 = f2; f2 = f3; f3 = f4;
        p0 = p1; p1 = p2; p2 = p3; p3 = p4; p4 = nw;
    }
    float integ = fmaf(12.0f, acc2, acc4) * (2.0f * 0.1f / 45.0f);
    float deriv = fmaf(25.0f, p4, fmaf(-48.0f, p3, fmaf(36.0f, p2,
                  fmaf(-16.0f, p1, 3.0f * p0)))) * (1.0f / 1.2f);
    ws[W_LF_IN + t] = deriv / p4;
    ws[W_IG_IN + t] = integ / (p4 * p4);
}

// ---------------------------------------------------------------- k_mat
// thread (s,t): 4x4 companion product over segment s (28 steps), s in [0,31)
__global__ __launch_bounds__(256) void k_mat(const float* __restrict__ energy,
                                             float* __restrict__ ws)
{
    const int bid = (int)blockIdx.x;
    const int s = bid / 48;                         // 0..30
    const int t = (bid % 48) * 256 + (int)threadIdx.x;
    const int l = t % 3, ei = t / 3;
    const float negE = -energy[ei];
    const int jstart = 5 + 28 * s;
    const float* gq = ws + W_GT + (size_t)jstart * 3 + l;
    float F0 = gq[-12] + negE, F1 = gq[-9] + negE, F2 = gq[-6] + negE, F3 = gq[-3] + negE;

    float ca, cb, cc_, cd;
    float ra[4] = {1,0,0,0}, rb[4] = {0,1,0,0}, rc[4] = {0,0,1,0}, rd[4] = {0,0,0,1};
#define MSTEP(FA,FB,FC,FD,RA,RB,RC,RD) \
    { COEF(gq,FA,FB,FC,FD) \
      RA[0] = fmaf(cd,RD[0], fmaf(cc_,RC[0], fmaf(cb,RB[0], ca*RA[0]))); \
      RA[1] = fmaf(cd,RD[1], fmaf(cc_,RC[1], fmaf(cb,RB[1], ca*RA[1]))); \
      RA[2] = fmaf(cd,RD[2], fmaf(cc_,RC[2], fmaf(cb,RB[2], ca*RA[2]))); \
      RA[3] = fmaf(cd,RD[3], fmaf(cc_,RC[3], fmaf(cb,RB[3], ca*RA[3]))); }
    #pragma unroll
    for (int it = 0; it < 7; ++it) {   // 28 steps, rotation restored
        MSTEP(F0,F1,F2,F3, ra,rb,rc,rd)
        MSTEP(F1,F2,F3,F0, rb,rc,rd,ra)
        MSTEP(F2,F3,F0,F1, rc,rd,ra,rb)
        MSTEP(F3,F0,F1,F2, rd,ra,rb,rc)
    }
#undef MSTEP
    // store rows (ra..rd = rows 0..3), layout [i=r*4+c][s][t]
    float* m = ws + W_MAT + t;
    #pragma unroll
    for (int c = 0; c < 4; ++c) {
        m[(size_t)(( 0 + c) * 31 + s) * kNCH] = ra[c];
        m[(size_t)(( 4 + c) * 31 + s) * kNCH] = rb[c];
        m[(size_t)(( 8 + c) * 31 + s) * kNCH] = rc[c];
        m[(size_t)((12 + c) * 31 + s) * kNCH] = rd[c];
    }
}

// ---------------------------------------------------------------- k_comb
// 1 thread/chain: head init + 31 serial mat-vec applies, states -> ws
__global__ __launch_bounds__(256) void k_comb(const float* __restrict__ energy,
                                              float* __restrict__ out,
                                              float* __restrict__ ws)
{
    const int t = (int)blockIdx.x * 256 + (int)threadIdx.x;
    const int l = t % 3, ei = t / 3;
    const float e = energy[ei];
    float* uinf = out + kNCH + (size_t)kMatch * kNCH;

    const float se  = sqrtf(fabsf(e));
    const float rfc = (l == 0) ? 1.0f : ((l == 1) ? (1.0f/3.0f) : (1.0f/15.0f));
    const float rt1 = (l == 0) ? (1.0f/3.0f) : ((l == 1) ? (1.0f/5.0f) : (1.0f/7.0f));
    const float rt2 = (l == 0) ? (1.0f/30.0f) : ((l == 1) ? (1.0f/70.0f) : (1.0f/126.0f));
    float pw[5];
    #pragma unroll
    for (int k = 0; k < 5; ++k) {
        float rinf = 99.6f + 0.1f * (float)k;
        float x  = rinf * se;
        float xl = (l == 0) ? 1.0f : ((l == 1) ? x : x * x);
        float h  = x * x * 0.5f;
        pw[k] = rinf * (xl * rfc * (1.0f + h * rt1 + (h * h) * rt2));
    }
    uinf[(size_t)899 * kNCH + t] = pw[4];

    float st0 = pw[1], st1 = pw[2], st2 = pw[3], st3 = pw[4];
    const float* m  = ws + W_MAT + t;
    float* stp      = ws + W_ST + t;
    #pragma unroll
    for (int ss = 0; ss < kSeg; ++ss) {
        stp[(size_t)(ss*4 + 0) * kNCH] = st0;
        stp[(size_t)(ss*4 + 1) * kNCH] = st1;
        stp[(size_t)(ss*4 + 2) * kNCH] = st2;
        stp[(size_t)(ss*4 + 3) * kNCH] = st3;
        if (ss < kSeg - 1) {
            float M[16];
            #pragma unroll
            for (int i = 0; i < 16; ++i) M[i] = m[(size_t)(i * 31 + ss) * kNCH];
            float n0 = fmaf(M[ 3],st3, fmaf(M[ 2],st2, fmaf(M[ 1],st1, M[ 0]*st0)));
            float n1 = fmaf(M[ 7],st3, fmaf(M[ 6],st2, fmaf(M[ 5],st1, M[ 4]*st0)));
            float n2 = fmaf(M[11],st3, fmaf(M[10],st2, fmaf(M[ 9],st1, M[ 8]*st0)));
            float n3 = fmaf(M[15],st3, fmaf(M[14],st2, fmaf(M[13],st1, M[12]*st0)));
            st0 = n0; st1 = n1; st2 = n2; st3 = n3;
        }
    }
}

// ---------------------------------------------------------------- k_replay
__global__ __launch_bounds__(256) void k_replay(const float* __restrict__ energy,
                                                float* __restrict__ out,
                                                float* __restrict__ ws)
{
    const int bid = (int)blockIdx.x;
    const int s = bid / 48;                          // 0..31
    const int t = (bid % 48) * 256 + (int)threadIdx.x;
    const int l = t % 3, ei = t / 3;
    const float negE = -energy[ei];
    float* uinf = out + kNCH + (size_t)kMatch * kNCH;
    const int jstart = 5 + 28 * s;
    int j = jstart;

    const float* gq = ws + W_GT + (size_t)jstart * 3 + l;
    float F0 = gq[-12] + negE, F1 = gq[-9] + negE, F2 = gq[-6] + negE, F3 = gq[-3] + negE;
    const float* stp = ws + W_ST + t;
    float p0 = stp[(size_t)(s*4 + 0) * kNCH];
    float p1 = stp[(size_t)(s*4 + 1) * kNCH];
    float p2 = stp[(size_t)(s*4 + 2) * kNCH];
    float p3 = stp[(size_t)(s*4 + 3) * kNCH];

    float ca, cb, cc_, cd;
    float acc4 = 0.0f, acc2 = 0.0f;
    float* ptr = uinf + (size_t)(903 - jstart) * kNCH + t;
#define RSTEP(FA,FB,FC,FD,PA,PB,PC,PD) \
    { COEF(gq,FA,FB,FC,FD) \
      float nw = fmaf(cd,PD, fmaf(cc_,PC, fmaf(cb,PB, ca*PA))); \
      PA = nw; *ptr = nw; ptr -= kNCH; \
      float v2 = nw*nw, v4 = v2*v2; \
      if (j >= 8) { int m = j & 3; \
        if (m == 1) acc2 += v2; \
        else acc4 += ((m == 3) ? 14.0f : 32.0f) * v4; } \
      else if (j == 7) acc4 += 7.0f * v4; \
      ++j; }

    float h0 = 0.0f;
    if (s < kSeg - 1) {
        #pragma unroll
        for (int it = 0; it < 7; ++it) {   // 28 steps
            RSTEP(F0,F1,F2,F3, p0,p1,p2,p3)
            RSTEP(F1,F2,F3,F0, p1,p2,p3,p0)
            RSTEP(F2,F3,F0,F1, p2,p3,p0,p1)
            RSTEP(F3,F0,F1,F2, p3,p0,p1,p2)
        }
    } else {
        #pragma unroll
        for (int it = 0; it < 6; ++it) {   // 24 steps
            RSTEP(F0,F1,F2,F3, p0,p1,p2,p3)
            RSTEP(F1,F2,F3,F0, p1,p2,p3,p0)
            RSTEP(F2,F3,F0,F1, p2,p3,p0,p1)
            RSTEP(F3,F0,F1,F2, p3,p0,p1,p2)
        }
        // window: p0=w893, p1=w894, p2=w895, p3=w896
        RSTEP(F0,F1,F2,F3, p0,p1,p2,p3)    // j=897 -> p0=w897
        h0 = p1;                            // w894, about to be overwritten
        RSTEP(F1,F2,F3,F0, p1,p2,p3,p0)    // j=898 -> p1=w898
        // head: h0=w894, p2=w895, p3=w896, p0=w897, p1=w898
    }
#undef RSTEP
    ws[W_A4 + (size_t)s * kNCH + t] = acc4;
    ws[W_A2 + (size_t)s * kNCH + t] = acc2;
    if (s == kSeg - 1) {
        float h1 = p2, h2 = p3, h3 = p0, h4 = p1;
        uinf[(size_t)0 * kNCH + t] = h0;
        uinf[(size_t)1 * kNCH + t] = h1;
        uinf[(size_t)2 * kNCH + t] = h2;
        uinf[(size_t)3 * kNCH + t] = h3;
        uinf[(size_t)4 * kNCH + t] = h4;
        ws[W_HD + (size_t)0 * kNCH + t] = h0;
        ws[W_HD + (size_t)1 * kNCH + t] = h1;
        ws[W_HD + (size_t)2 * kNCH + t] = h2;
        ws[W_HD + (size_t)3 * kNCH + t] = h3;
        ws[W_HD + (size_t)4 * kNCH + t] = h4;
    }
}

// ---------------------------------------------------------------- final
__global__ __launch_bounds__(256) void final_kernel(const float* __restrict__ energy,
                                                    const float* __restrict__ ws,
                                                    float* __restrict__ out)
{
    const int t = (int)blockIdx.x * 256 + (int)threadIdx.x;
    const int l = t % 3, ei = t / 3;
    float a4 = 0.0f, a2 = 0.0f;
    #pragma unroll
    for (int ss = 0; ss < kSeg; ++ss) {
        a4 += ws[W_A4 + (size_t)ss * kNCH + t];
        a2 += ws[W_A2 + (size_t)ss * kNCH + t];
    }
    float h0 = ws[W_HD + (size_t)0 * kNCH + t];
    float h1 = ws[W_HD + (size_t)1 * kNCH + t];
    float h2 = ws[W_HD + (size_t)2 * kNCH + t];
    float h3 = ws[W_HD + (size_t)3 * kNCH + t];
    float h4 = ws[W_HD + (size_t)4 * kNCH + t];
    float q0 = h0*h0, q1 = h1*h1, q2 = h2*h2, q3 = h3*h3, q4 = h4*h4;
    a4 += 7.0f*q0*q0 + 32.0f*q1*q1 + 32.0f*q3*q3 + 14.0f*q4*q4;
    a2 += q2;
    float integ = fmaf(12.0f, a2, a4) * (2.0f * 0.1f / 45.0f);

    // lfunc_out is energy-axis reversed: partner chain's head values
    const int tp = (kNE - 1 - ei) * 3 + l;
    float g0 = ws[W_HD + (size_t)0 * kNCH + tp];
    float g1 = ws[W_HD + (size_t)1 * kNCH + tp];
    float g2 = ws[W_HD + (size_t)2 * kNCH + tp];
    float g3 = ws[W_HD + (size_t)3 * kNCH + tp];
    float g4 = ws[W_HD + (size_t)4 * kNCH + tp];
    float lf_out = (fmaf(25.0f, g0, fmaf(-48.0f, g1, fmaf(36.0f, g2,
                   fmaf(-16.0f, g3, 3.0f * g4)))) * (1.0f / 1.2f)) / g0;

    float den = integ / (h0 * h0) + ws[W_IG_IN + t];
    float lf_in = ws[W_LF_IN + t];
    out[t] = energy[ei] - (lf_out - lf_in) / den;
}

extern "C" void kernel_launch(void* const* d_in, const int* in_sizes, int n_in,
                              void* d_out, int out_size, void* d_ws, size_t ws_size,
                              hipStream_t stream) {
    (void)in_sizes; (void)n_in; (void)out_size; (void)ws_size;
    const float* energy = (const float*)d_in[0];
    float* out = (float*)d_out;
    float* ws  = (float*)d_ws;
    k_zero  <<<48,        256, 0, stream>>>(energy, out, ws);
    k_mat   <<<31 * 48,   256, 0, stream>>>(energy, ws);
    k_comb  <<<48,        256, 0, stream>>>(energy, out, ws);
    k_replay<<<32 * 48,   256, 0, stream>>>(energy, out, ws);
    final_kernel<<<48,    256, 0, stream>>>(energy, ws, out);
}

// Round 7
// 87.871 us; speedup vs baseline: 1.3520x; 1.3520x over previous
//
#include <hip/hip_runtime.h>

// EvalEig round 7: test store-coalescing theory (T1). Monolith (r5 machinery:
// LDS g-table, poly 1/(1-x), 4x4 transfer matrices) reshaped to 32 chains x
// 16 segments (512 thr): wave = 32 consecutive chains -> every u_infty store
// is full 128B lines (r2/3/5 waves stored 4 scattered 64B half-lines -> L2
// partial-line RMW suspected as the unexplained ~4x over issue model).
// Uniform 56-step segments (s15 overlaps 2 duplicate steps, identical values)
// + register-resident quadrature weights: zero per-step branches/divergence.

namespace {
constexpr int kNE    = 4096;
constexpr int kNCH   = kNE * 3;        // 12288 chains
constexpr int kMatch = 100;
constexpr float kC   = 3.0f / 40.0f * 0.01f;
constexpr float kK1  = 13.0f / 15.0f * 0.01f;
constexpr float kK2  = 7.0f / 60.0f * 0.01f;
constexpr int kSeg        = 16;
constexpr int kCPB        = 32;           // chains per block
constexpr int kZeroBlocks = kNCH / 512;   // 24
constexpr int kInfBlocks  = kNCH / kCPB;  // 384
}

__device__ __forceinline__ float rcp_f(float x) { return __builtin_amdgcn_rcpf(x); }
__device__ __forceinline__ float rcp_nr(float x) {
    float r = __builtin_amdgcn_rcpf(x);
    return fmaf(fmaf(-x, r, 1.0f), r, r);
}

__global__ __launch_bounds__(512) void solve_kernel(const float* __restrict__ energy,
                                                    float* __restrict__ out,
                                                    float* __restrict__ ws)
{
    __shared__ float gt[899 * 3];                 // 10.8 KB
    __shared__ float sPT[16][15][kCPB];           // 30 KB: [row*4+col][seg][chain]
    __shared__ float sSt[kSeg][4][kCPB];          // 8 KB:  [seg][comp][chain]
    float* sR4 = &sPT[0][0][0];                   // aliased after phase 2
    float* sR2 = sR4 + kSeg * kCPB;

    const int bid = (int)blockIdx.x;
    const int tid = (int)threadIdx.x;
    float* uzero = out + kNCH;
    float* uinf  = out + kNCH + (size_t)kMatch * kNCH;

    if (bid < kZeroBlocks) {
        // ---------------- u_zero: outward solve, 94 steps, 1 thread/chain ----
        const int t  = bid * 512 + tid;
        const int l  = t % 3;
        const int ei = t / 3;
        const float e = energy[ei], negE = -e;
        const float ll1 = (float)(l * (l + 1));
        const float rdiv = (l == 0) ? 0.5f : ((l == 1) ? 0.25f : (1.0f/6.0f));
        float p0,p1,p2,p3,p4;
        {
            float pw[5];
            #pragma unroll
            for (int k = 0; k < 5; ++k) {
                float r = 0.1f * (float)(k + 1);
                float rl1 = (l == 0) ? r : ((l == 1) ? r*r : r*r*r);
                pw[k] = rl1 - (rl1 * r) * rdiv;
                uzero[(size_t)k * kNCH + t] = pw[k];
            }
            uzero[(size_t)5 * kNCH + t] = pw[4];
            p0=pw[0]; p1=pw[1]; p2=pw[2]; p3=pw[3]; p4=pw[4];
        }
        float acc4, acc2;
        {
            float q0=p0*p0, q1=p1*p1, q2=p2*p2, q3=p3*p3, q4=p4*p4;
            acc4 = 7.0f*q0*q0 + 32.0f*q1*q1 + 32.0f*q3*q3 + 14.0f*q4*q4 + 32.0f*q4*q4;
            acc2 = q2;
        }
        float f0, f1, f2, f3;
        {
            float i1 = rcp_f(0.2f), i2 = rcp_f(0.3f), i3 = rcp_f(0.4f), i4 = rcp_f(0.5f);
            f0 = fmaf(i1, fmaf(ll1, i1, -1.0f), negE);
            f1 = fmaf(i2, fmaf(ll1, i2, -1.0f), negE);
            f2 = fmaf(i3, fmaf(ll1, i3, -1.0f), negE);
            f3 = fmaf(i4, fmaf(ll1, i4, -1.0f), negE);
        }
        float* ptr = uzero + (size_t)6 * kNCH + t;
        #pragma unroll 4
        for (int j = 5; j <= 98; ++j) {
            float ri = rcp_f(fmaf((float)j, 0.1f, 0.1f));
            float f4 = fmaf(ri, fmaf(ll1, ri, -1.0f), negE);
            float iv = rcp_f(fmaf(-kC, f4, 1.0f));
            float a  = fmaf(kC  * f0, iv, -1.0f);
            float b  = fmaf(kK1 * f1, iv,  2.0f);
            float cc = fmaf(kK2 * f2, iv, -2.0f);
            float d  = fmaf(kK1 * f3, iv,  2.0f);
            float nw = fmaf(d, p4, fmaf(cc, p3, fmaf(b, p2, a * p1)));
            *ptr = nw; ptr += kNCH;
            float v2 = nw*nw, v4 = v2*v2;
            if (j <= 94) {
                int m = (j + 1) & 3;
                if (m == 2)      acc2 += v2;
                else if (m == 0) acc4 += 14.0f * v4;
                else             acc4 += 32.0f * v4;
            } else if (j == 95) {
                acc4 += 7.0f * v4;
            }
            f0 = f1; f1 = f2; f2 = f3; f3 = f4;
            p0 = p1; p1 = p2; p2 = p3; p3 = p4; p4 = nw;
        }
        float integ = fmaf(12.0f, acc2, acc4) * (2.0f * 0.1f / 45.0f);
        float deriv = fmaf(25.0f, p4, fmaf(-48.0f, p3, fmaf(36.0f, p2,
                      fmaf(-16.0f, p1, 3.0f * p0)))) * (1.0f / 1.2f);
        ws[2 * kNCH + t] = deriv / p4;
        ws[3 * kNCH + t] = integ / (p4 * p4);
        return;
    }

    // ---------------- u_infty: 16-segment inward solve ----------------
    for (int jj = tid; jj < 899; jj += 512) {
        float ri = rcp_nr(fmaf((float)jj, -0.1f, 100.0f));
        gt[jj * 3 + 0] = -ri;
        gt[jj * 3 + 1] = ri * fmaf(2.0f, ri, -1.0f);
        gt[jj * 3 + 2] = ri * fmaf(6.0f, ri, -1.0f);
    }
    __syncthreads();

    const int b = bid - kZeroBlocks;
    const int g = tid & 31;            // chain within block (32 consecutive)
    const int s = tid >> 5;            // segment 0..15 (2 per wave)
    const int t = b * kCPB + g;
    const int l  = t % 3;
    const int ei = t / 3;
    const float e = energy[ei], negE = -e;
    // seg s: jstart = 5+56s for s<15; s=15 starts at 843 (overlaps 2 dup steps)
    const int jstart = (s < 15) ? (5 + 56 * s) : 843;

    const float ff0 = gt[(jstart - 4) * 3 + l] + negE;
    const float ff1 = gt[(jstart - 3) * 3 + l] + negE;
    const float ff2 = gt[(jstart - 2) * 3 + l] + negE;
    const float ff3 = gt[(jstart - 1) * 3 + l] + negE;
    float F0 = ff0, F1 = ff1, F2 = ff2, F3 = ff3;
    const float* gp0 = &gt[jstart * 3 + l];
    const float* gp = gp0;

    float ca, cb, cc_, cd;
#define COEF(FA,FB,FC,FD) \
    { float f4 = *gp + negE; gp += 3; \
      float x  = kC * f4; \
      float iv = fmaf(x, x, x) + 1.0f; \
      ca  = fmaf(kC  * FA, iv, -1.0f); \
      cb  = fmaf(kK1 * FB, iv,  2.0f); \
      cc_ = fmaf(kK2 * FC, iv, -2.0f); \
      cd  = fmaf(kK1 * FD, iv,  2.0f); \
      FA = f4; }

#define MSTEP(FA,FB,FC,FD,RA,RB,RC,RD) \
    { COEF(FA,FB,FC,FD) \
      RA[0] = fmaf(cd,RD[0], fmaf(cc_,RC[0], fmaf(cb,RB[0], ca*RA[0]))); \
      RA[1] = fmaf(cd,RD[1], fmaf(cc_,RC[1], fmaf(cb,RB[1], ca*RA[1]))); \
      RA[2] = fmaf(cd,RD[2], fmaf(cc_,RC[2], fmaf(cb,RB[2], ca*RA[2]))); \
      RA[3] = fmaf(cd,RD[3], fmaf(cc_,RC[3], fmaf(cb,RB[3], ca*RA[3]))); }

    // ---- phase 1: companion products. s<14: 56 steps; s=14: 54 steps
    // (state for s15 needed at j=843 = 789+54). s=15: no matrix.
    if (s < 14) {
        float ra[4] = {1,0,0,0}, rb[4] = {0,1,0,0}, rc[4] = {0,0,1,0}, rd[4] = {0,0,0,1};
        for (int it = 0; it < 14; ++it) {  // 56 steps, rotation restored
            MSTEP(F0,F1,F2,F3, ra,rb,rc,rd)
            MSTEP(F1,F2,F3,F0, rb,rc,rd,ra)
            MSTEP(F2,F3,F0,F1, rc,rd,ra,rb)
            MSTEP(F3,F0,F1,F2, rd,ra,rb,rc)
        }
        #pragma unroll
        for (int c = 0; c < 4; ++c) {
            sPT[ 0+c][s][g] = ra[c]; sPT[ 4+c][s][g] = rb[c];
            sPT[ 8+c][s][g] = rc[c]; sPT[12+c][s][g] = rd[c];
        }
    } else if (s == 14) {
        float ra[4] = {1,0,0,0}, rb[4] = {0,1,0,0}, rc[4] = {0,0,1,0}, rd[4] = {0,0,0,1};
        for (int it = 0; it < 13; ++it) {  // 52 steps
            MSTEP(F0,F1,F2,F3, ra,rb,rc,rd)
            MSTEP(F1,F2,F3,F0, rb,rc,rd,ra)
            MSTEP(F2,F3,F0,F1, rc,rd,ra,rb)
            MSTEP(F3,F0,F1,F2, rd,ra,rb,rc)
        }
        MSTEP(F0,F1,F2,F3, ra,rb,rc,rd)    // +2 = 54; logical order rc,rd,ra,rb
        MSTEP(F1,F2,F3,F0, rb,rc,rd,ra)
        #pragma unroll
        for (int c = 0; c < 4; ++c) {
            sPT[ 0+c][s][g] = rc[c]; sPT[ 4+c][s][g] = rd[c];
            sPT[ 8+c][s][g] = ra[c]; sPT[12+c][s][g] = rb[c];
        }
    }
    __syncthreads();

    // ---- phase 2: per-chain serial combine (lanes tid 0..31)
    if (s == 0) {
        const float se  = sqrtf(fabsf(e));
        const float rfc = (l == 0) ? 1.0f : ((l == 1) ? (1.0f/3.0f) : (1.0f/15.0f));
        const float rt1 = (l == 0) ? (1.0f/3.0f) : ((l == 1) ? (1.0f/5.0f) : (1.0f/7.0f));
        const float rt2 = (l == 0) ? (1.0f/30.0f) : ((l == 1) ? (1.0f/70.0f) : (1.0f/126.0f));
        float pw[5];
        #pragma unroll
        for (int k = 0; k < 5; ++k) {
            float rinf = 99.6f + 0.1f * (float)k;
            float x  = rinf * se;
            float xl = (l == 0) ? 1.0f : ((l == 1) ? x : x * x);
            float h  = x * x * 0.5f;
            pw[k] = rinf * (xl * rfc * (1.0f + h * rt1 + (h * h) * rt2));
        }
        uinf[(size_t)899 * kNCH + t] = pw[4];
        float st0 = pw[1], st1 = pw[2], st2 = pw[3], st3 = pw[4];
        for (int ss = 0; ss < kSeg; ++ss) {
            sSt[ss][0][g] = st0; sSt[ss][1][g] = st1;
            sSt[ss][2][g] = st2; sSt[ss][3][g] = st3;
            if (ss < kSeg - 1) {
                float n0 = fmaf(sPT[ 3][ss][g],st3, fmaf(sPT[ 2][ss][g],st2,
                           fmaf(sPT[ 1][ss][g],st1, sPT[ 0][ss][g]*st0)));
                float n1 = fmaf(sPT[ 7][ss][g],st3, fmaf(sPT[ 6][ss][g],st2,
                           fmaf(sPT[ 5][ss][g],st1, sPT[ 4][ss][g]*st0)));
                float n2 = fmaf(sPT[11][ss][g],st3, fmaf(sPT[10][ss][g],st2,
                           fmaf(sPT[ 9][ss][g],st1, sPT[ 8][ss][g]*st0)));
                float n3 = fmaf(sPT[15][ss][g],st3, fmaf(sPT[14][ss][g],st2,
                           fmaf(sPT[13][ss][g],st1, sPT[12][ss][g]*st0)));
                st0 = n0; st1 = n1; st2 = n2; st3 = n3;
            }
        }
    }
    __syncthreads();

    // ---- phase 3: uniform 56-step replay, register-resident quad weights
    // slot weight tables: (W -> acc4 += W*v4, V -> acc2 += V*v2)
    float W0[4] = {0.0f, 32.0f, 14.0f, 32.0f};   // group 0 (j = jstart..+3)
    float V0[4] = {1.0f, 0.0f, 0.0f, 0.0f};
    float WR[4] = {0.0f, 32.0f, 14.0f, 32.0f};   // groups 1..13 (jstart≡1 mod 4)
    float VR[4] = {1.0f, 0.0f, 0.0f, 0.0f};
    if (s == 0) {       // j=5,6 weight 0; j=7 -> 7*v4; j=8 -> 32*v4
        W0[0]=0; V0[0]=0; W0[1]=0; V0[1]=0; W0[2]=7.0f; V0[2]=0; W0[3]=32.0f; V0[3]=0;
    } else if (s == 15) {   // jstart=843 ≡ 3 mod 4: slots j≡3,0,1,2
        WR[0]=14.0f; VR[0]=0; WR[1]=32.0f; VR[1]=0; WR[2]=0; VR[2]=1.0f; WR[3]=32.0f; VR[3]=0;
        // group 0: j=843,844 duplicated with s14 -> skip; j=845 -> acc2; j=846 -> 32
        W0[0]=0; V0[0]=0; W0[1]=0; V0[1]=0; W0[2]=0; V0[2]=1.0f; W0[3]=32.0f; V0[3]=0;
    }

    gp = gp0;
    F0 = ff0; F1 = ff1; F2 = ff2; F3 = ff3;
    float p0 = sSt[s][0][g], p1 = sSt[s][1][g], p2 = sSt[s][2][g], p3 = sSt[s][3][g];
    float acc4 = 0.0f, acc2 = 0.0f;
    float* ptr = uinf + (size_t)(903 - jstart) * kNCH + t;
#define RSTEPW(FA,FB,FC,FD,PA,PB,PC,PD,W,V,K) \
    { COEF(FA,FB,FC,FD) \
      float nw = fmaf(cd,PD, fmaf(cc_,PC, fmaf(cb,PB, ca*PA))); \
      PA = nw; *ptr = nw; ptr -= kNCH; \
      float v2 = nw*nw, v4 = v2*v2; \
      acc4 = fmaf(W[K], v4, acc4); \
      acc2 = fmaf(V[K], v2, acc2); }
#define GROUP(W,V) \
    RSTEPW(F0,F1,F2,F3, p0,p1,p2,p3, W,V,0) \
    RSTEPW(F1,F2,F3,F0, p1,p2,p3,p0, W,V,1) \
    RSTEPW(F2,F3,F0,F1, p2,p3,p0,p1, W,V,2) \
    RSTEPW(F3,F0,F1,F2, p3,p0,p1,p2, W,V,3)

    GROUP(W0,V0)                               // group 0
    for (int it = 0; it < 12; ++it) { GROUP(WR,VR) }   // groups 1..12
    float h0 = p3;                             // s==15: w894 (after 13 groups)
    GROUP(WR,VR)                               // group 13 -> j .. jstart+55
#undef GROUP
#undef RSTEPW

    sR4[s * kCPB + g] = acc4;   // aliases sPT (done after phase 2)
    sR2[s * kCPB + g] = acc2;
    __syncthreads();

    if (s == kSeg - 1) {
        float a4 = 0.0f, a2 = 0.0f;
        #pragma unroll
        for (int ss = 0; ss < kSeg; ++ss) {
            a4 += sR4[ss * kCPB + g]; a2 += sR2[ss * kCPB + g];
        }
        // after full 56 steps: p0..p3 = w895..w898 (rotation restored)
        float h1 = p0, h2 = p1, h3 = p2, h4 = p3;
        uinf[(size_t)0 * kNCH + t] = h0;
        uinf[(size_t)1 * kNCH + t] = h1;
        uinf[(size_t)2 * kNCH + t] = h2;
        uinf[(size_t)3 * kNCH + t] = h3;
        uinf[(size_t)4 * kNCH + t] = h4;
        float q0 = h0*h0, q1 = h1*h1, q2 = h2*h2, q3 = h3*h3, q4 = h4*h4;
        a4 += 7.0f*q0*q0 + 32.0f*q1*q1 + 32.0f*q3*q3 + 14.0f*q4*q4;
        a2 += q2;
        float integ = fmaf(12.0f, a2, a4) * (2.0f * 0.1f / 45.0f);
        float deriv = fmaf(25.0f, h0, fmaf(-48.0f, h1, fmaf(36.0f, h2,
                      fmaf(-16.0f, h3, 3.0f * h4)))) * (1.0f / 1.2f);
        ws[t]        = deriv / h0;            // lfunc_out (pre energy-reversal)
        ws[kNCH + t] = integ / (h0 * h0);     // integ_out / u_infty[0]^2
    }
#undef MSTEP
#undef COEF
}

__global__ __launch_bounds__(256) void final_kernel(const float* __restrict__ energy,
                                                    const float* __restrict__ ws,
                                                    float* __restrict__ out)
{
    int t = (int)blockIdx.x * 256 + (int)threadIdx.x;
    if (t >= kNCH) return;
    int l = t % 3, ei = t / 3;
    float lf_out = ws[(kNE - 1 - ei) * 3 + l];   // energy-axis reversed
    float lf_in  = ws[2 * kNCH + t];
    float den    = ws[kNCH + t] + ws[3 * kNCH + t];
    out[t] = energy[ei] - (lf_out - lf_in) / den;
}

extern "C" void kernel_launch(void* const* d_in, const int* in_sizes, int n_in,
                              void* d_out, int out_size, void* d_ws, size_t ws_size,
                              hipStream_t stream) {
    (void)in_sizes; (void)n_in; (void)out_size; (void)ws_size;
    const float* energy = (const float*)d_in[0];
    float* out = (float*)d_out;
    float* ws  = (float*)d_ws;   // 4*12288 floats = 192 KB scratch
    solve_kernel<<<kZeroBlocks + kInfBlocks, 512, 0, stream>>>(energy, out, ws);
    final_kernel<<<kNCH / 256, 256, 0, stream>>>(energy, ws, out);
}